// Round 7
// baseline (218.763 us; speedup 1.0000x reference)
//
#include <hip/hip_runtime.h>
#include <hip/hip_bf16.h>

#define DEVI __device__ __forceinline__

// Problem constants (fixed by the reference)
constexpr int Bb  = 2;
constexpr int Ss  = 2048;
constexpr int Dd  = 1024;
constexpr int Hh  = 16;
constexpr int HDh = 64;
constexpr int Mr  = Bb * Ss;      // 4096 rows in all GEMMs
constexpr float kEps = 1e-5f;
// kScale * log2(e), folded into the Q projection so flash uses raw 2^x
constexpr float kQScale = 0.18033688011112043f;

typedef unsigned short u16;
typedef unsigned int   u32;
typedef u16 u16x8 __attribute__((ext_vector_type(8)));
typedef u16 u16x4 __attribute__((ext_vector_type(4)));
typedef __attribute__((ext_vector_type(8)))  short s16x8;
typedef __attribute__((ext_vector_type(16))) float f32x16;
typedef __attribute__((ext_vector_type(4)))  u32   u32x4;

DEVI float bf2f(u16 u) {
  return __builtin_bit_cast(float, ((unsigned int)u) << 16);
}
DEVI u16 f2bf(float f) {  // round-to-nearest-even, finite values only
  unsigned int x = __builtin_bit_cast(unsigned int, f);
  return (u16)((x + 0x7FFFu + ((x >> 16) & 1u)) >> 16);
}
DEVI u32 cvt_pk_bf16(float a, float b) {  // HW packed f32x2 -> bf16x2, RNE
  u32 r;
  asm("v_cvt_pk_bf16_f32 %0, %1, %2" : "=v"(r) : "v"(a), "v"(b));
  return r;
}
DEVI float vexp2(float x) {  // 2^x on the TRANS pipe, no pre-multiply
  float r;
  asm("v_exp_f32 %0, %1" : "=v"(r) : "v"(x));
  return r;
}

// global -> LDS direct copy, 16B per lane (flash only now).
DEVI void gload_lds16(const void* g, void* l) {
  __builtin_amdgcn_global_load_lds(
      (const __attribute__((address_space(1))) unsigned int*)(unsigned long long)(size_t)g,
      (__attribute__((address_space(3))) unsigned int*)(unsigned int)(size_t)l,
      16, 0, 0);
}

// ---------------------------------------------------------------------------
// f32 -> bf16 elementwise convert. 8 elems/thread, coalesced. grid.y selects
// matrix (1 or 2 matrices per launch).
// ---------------------------------------------------------------------------
__global__ __launch_bounds__(256) void conv_bf16_k(
    const float* __restrict__ X0, const float* __restrict__ X1,
    u16* __restrict__ Y0, u16* __restrict__ Y1) {
  const float* X = blockIdx.y ? X1 : X0;
  u16*         Y = blockIdx.y ? Y1 : Y0;
  const size_t i = ((size_t)blockIdx.x * 256 + threadIdx.x) * 8;
  const float4 a = *(const float4*)(X + i);
  const float4 b = *(const float4*)(X + i + 4);
  u32x4 o;
  o[0] = cvt_pk_bf16(a.x, a.y);
  o[1] = cvt_pk_bf16(a.z, a.w);
  o[2] = cvt_pk_bf16(b.x, b.y);
  o[3] = cvt_pk_bf16(b.z, b.w);
  *(u32x4*)(Y + i) = o;
}

// ---------------------------------------------------------------------------
// Weight transpose+convert: Wt[n][k] = bf16(W[k][n]), 1024x1024, 4 matrices.
// ---------------------------------------------------------------------------
__global__ __launch_bounds__(256) void trans_w_k(
    const float* __restrict__ W0, const float* __restrict__ W1,
    const float* __restrict__ W2, const float* __restrict__ W3,
    u16* __restrict__ WtBase) {
  __shared__ u16 Tl[64 * 64];
  const int t  = threadIdx.x;
  const int k0 = blockIdx.x * 64, n0 = blockIdx.y * 64;
  const int z  = blockIdx.z;
  const float* W = z == 0 ? W0 : z == 1 ? W1 : z == 2 ? W2 : W3;
  u16* out = WtBase + (size_t)z * 1024 * 1024;
#pragma unroll
  for (int i = 0; i < 4; ++i) {
    const int idx = t + i * 256;
    const int r = idx >> 4, c4 = (idx & 15) << 2;
    const float4 v = *(const float4*)(W + (size_t)(k0 + r) * 1024 + n0 + c4);
    u16x4 p;
    p[0] = f2bf(v.x); p[1] = f2bf(v.y); p[2] = f2bf(v.z); p[3] = f2bf(v.w);
    *(u16x4*)&Tl[r * 64 + (c4 ^ (8 * (r & 7)))] = p;
  }
  __syncthreads();
#pragma unroll
  for (int i = 0; i < 2; ++i) {
    const int idx = t + i * 256;
    const int n = idx & 63, r8 = (idx >> 6) * 8;
    u16x8 o;
#pragma unroll
    for (int j = 0; j < 8; ++j) o[j] = Tl[(r8 + j) * 64 + (n ^ (8 * ((r8 + j) & 7)))];
    *(u16x8*)(out + (size_t)(n0 + n) * 1024 + k0 + r8) = o;
  }
}

// ---------------------------------------------------------------------------
// Register-staged MFMA GEMM: C[4096][1024] = A[4096][1024] @ Wt[1024][1024]^T
// + bias (x esc). NO LDS, NO barriers: each wave owns a 64x64 output tile and
// loads its MFMA fragments DIRECTLY into registers (per-lane identity of the
// old gload_lds->ds_read path). X/Y register double-buffer; the compiler's
// per-register dependency tracking emits counted vmcnt waits (no vmcnt(0)
// drain, no barrier convoy). Block = 4 independent waves (2x2 of 64x64).
// XCD-aware bijective swizzle keeps each XCD chunk's W panel L2-resident.
// MODE 0: bf16 row-major out (esc-scaled)
// MODE 1: bf16 written transposed into Vtg[b][n][s]
// MODE 2: f32 row-major out
// ---------------------------------------------------------------------------
template <int MODE>
__global__ __launch_bounds__(256) void gemm_reg_k(
    const u16* __restrict__ A0, const u16* __restrict__ A1,
    const u16* __restrict__ Wt0, const u16* __restrict__ Wt1,
    const float* b0, const float* b1, void* C0, void* C1,
    float e0, float e1) {
  constexpr int K = 1024, N = 1024;
  const int z = blockIdx.z;
  const u16*   A    = z ? A1 : A0;
  const u16*   Wt   = z ? Wt1 : Wt0;
  const float* bias = z ? b1 : b0;
  void*        Cv   = z ? C1 : C0;
  const float  esc  = z ? e1 : e0;

  const int t = threadIdx.x;
  const int lane = t & 63, w = t >> 6;
  const int l31 = lane & 31, g2 = lane >> 5;
  // XCD swizzle (256 blocks/z-slice, 8 XCDs, chunk 32)
  const int id  = blockIdx.y * 8 + blockIdx.x;
  const int sid = (id & 7) * 32 + (id >> 3);
  const int m0 = (sid >> 3) * 128, n0 = (sid & 7) * 128;
  const int wr = w >> 1, wc = w & 1;

  // per-lane fragment base pointers (A tiles 2wr..2wr+1, W tiles 2wc..2wc+1;
  // lane holds row/col l31, k = k0 + 16s + 8*g2 + 0..7)
  const u16* a0p = A  + (size_t)(m0 + (2 * wr + 0) * 32 + l31) * K + 8 * g2;
  const u16* a1p = A  + (size_t)(m0 + (2 * wr + 1) * 32 + l31) * K + 8 * g2;
  const u16* w0p = Wt + (size_t)(n0 + (2 * wc + 0) * 32 + l31) * K + 8 * g2;
  const u16* w1p = Wt + (size_t)(n0 + (2 * wc + 1) * 32 + l31) * K + 8 * g2;

  f32x16 acc00, acc01, acc10, acc11;
#pragma unroll
  for (int r = 0; r < 16; ++r) { acc00[r] = 0.f; acc01[r] = 0.f; acc10[r] = 0.f; acc11[r] = 0.f; }

  // R[0..1] = A tile0 slabs s0/s1, R[2..3] = A tile1, R[4..5] = W tile0,
  // R[6..7] = W tile1 (all constant-indexed -> registers)
  s16x8 X[8], Y[8];
  auto loadset = [&](s16x8* R, int k0) {
    R[0] = *(const s16x8*)(a0p + k0);  R[1] = *(const s16x8*)(a0p + k0 + 16);
    R[2] = *(const s16x8*)(a1p + k0);  R[3] = *(const s16x8*)(a1p + k0 + 16);
    R[4] = *(const s16x8*)(w0p + k0);  R[5] = *(const s16x8*)(w0p + k0 + 16);
    R[6] = *(const s16x8*)(w1p + k0);  R[7] = *(const s16x8*)(w1p + k0 + 16);
  };
  auto compute = [&](const s16x8* R) {
#pragma unroll
    for (int s = 0; s < 2; ++s) {
      if constexpr (MODE == 1) {
        // C col = n (A-op = X): transposed store orientation
        acc00 = __builtin_amdgcn_mfma_f32_32x32x16_bf16(R[0 + s], R[4 + s], acc00, 0, 0, 0);
        acc01 = __builtin_amdgcn_mfma_f32_32x32x16_bf16(R[0 + s], R[6 + s], acc01, 0, 0, 0);
        acc10 = __builtin_amdgcn_mfma_f32_32x32x16_bf16(R[2 + s], R[4 + s], acc10, 0, 0, 0);
        acc11 = __builtin_amdgcn_mfma_f32_32x32x16_bf16(R[2 + s], R[6 + s], acc11, 0, 0, 0);
      } else {
        // C col = m (A-op = W): row-major store orientation
        acc00 = __builtin_amdgcn_mfma_f32_32x32x16_bf16(R[4 + s], R[0 + s], acc00, 0, 0, 0);
        acc01 = __builtin_amdgcn_mfma_f32_32x32x16_bf16(R[4 + s], R[2 + s], acc01, 0, 0, 0);
        acc10 = __builtin_amdgcn_mfma_f32_32x32x16_bf16(R[6 + s], R[0 + s], acc10, 0, 0, 0);
        acc11 = __builtin_amdgcn_mfma_f32_32x32x16_bf16(R[6 + s], R[2 + s], acc11, 0, 0, 0);
      }
    }
  };

  loadset(X, 0);
  loadset(Y, 32);
  for (int k0 = 0; k0 < K; k0 += 64) {
    compute(X);
    if (k0 + 64 < K) loadset(X, k0 + 64);
    compute(Y);
    if (k0 + 96 < K) loadset(Y, k0 + 96);
  }

  if constexpr (MODE == 1) {
    auto storeV = [&](const f32x16& a, int i, int j) {
      const int n = n0 + (2 * wc + j) * 32 + l31;
      const float bn = bias[n];
      u16* vout = (u16*)Cv + ((size_t)(m0 >> 11)) * (1024 * 2048) + (size_t)n * 2048 +
                  (m0 & 2047) + (2 * wr + i) * 32;
#pragma unroll
      for (int c = 0; c < 4; ++c) {
        u16x4 o;
#pragma unroll
        for (int rr = 0; rr < 4; ++rr) o[rr] = f2bf(a[4 * c + rr] + bn);
        *(u16x4*)(vout + 8 * c + 4 * g2) = o;
      }
    };
    storeV(acc00, 0, 0); storeV(acc01, 0, 1); storeV(acc10, 1, 0); storeV(acc11, 1, 1);
  } else {
    auto storeNM = [&](const f32x16& a, int i, int j) {
      const int m = m0 + (2 * wr + j) * 32 + l31;
#pragma unroll
      for (int c = 0; c < 4; ++c) {
        const int nb = n0 + (2 * wc + i) * 32 + 8 * c + 4 * g2;
        const float4 b4 = *(const float4*)&bias[nb];
        if constexpr (MODE == 2) {
          float4 v;
          v.x = a[4 * c + 0] + b4.x; v.y = a[4 * c + 1] + b4.y;
          v.z = a[4 * c + 2] + b4.z; v.w = a[4 * c + 3] + b4.w;
          *(float4*)((float*)Cv + (size_t)m * N + nb) = v;
        } else {
          u16x4 o;
          o[0] = f2bf((a[4 * c + 0] + b4.x) * esc); o[1] = f2bf((a[4 * c + 1] + b4.y) * esc);
          o[2] = f2bf((a[4 * c + 2] + b4.z) * esc); o[3] = f2bf((a[4 * c + 3] + b4.w) * esc);
          *(u16x4*)((u16*)Cv + (size_t)m * N + nb) = o;
        }
      }
    };
    storeNM(acc00, 0, 0); storeNM(acc01, 0, 1); storeNM(acc10, 1, 0); storeNM(acc11, 1, 1);
  }
}

// ---------------------------------------------------------------------------
// MFMA flash attention (unchanged from round 6, verified): double-buffered,
// exp2-domain softmax, permlane32_swap P-exchange, setprio, XCD swizzle.
// Ob aliases Qb (disjoint per block, read-before-write).
// ---------------------------------------------------------------------------
__global__ __launch_bounds__(256) void flash_mfma_k(
    const u16* Qb, const u16* __restrict__ Kb,
    const u16* __restrict__ Vtg, u16* Ob) {
  __shared__ u16 smem[16384];
  const int t    = threadIdx.x;
  const int lane = t & 63;
  const int w    = t >> 6;
  const int l31  = lane & 31, g2 = lane >> 5;
  // swizzle: 512 blocks, 8 XCDs, chunk 64
  const int hid = (blockIdx.z * 16 + blockIdx.y) * 16 + blockIdx.x;
  const int sid = (hid & 7) * 64 + (hid >> 3);
  const int h = (sid >> 4) & 15, b = sid >> 8;
  const int q0 = (sid & 15) * 128 + w * 32;

  s16x8 qf0, qf1, qf2, qf3;
  {
    const u16* qp = Qb + ((size_t)(b * Ss + q0 + l31)) * Dd + h * HDh + 8 * g2;
    qf0 = *(const s16x8*)(qp);
    qf1 = *(const s16x8*)(qp + 16);
    qf2 = *(const s16x8*)(qp + 32);
    qf3 = *(const s16x8*)(qp + 48);
  }

  f32x16 accO0, accO1;
#pragma unroll
  for (int r = 0; r < 16; ++r) { accO0[r] = 0.f; accO1[r] = 0.f; }
  float l_run = 0.f;

  const int f0 = 2 * w, f1 = 2 * w + 1;
  const u16* kg0 = Kb + ((size_t)(b * Ss + 32 * (f0 >> 2) + l31)) * Dd + h * HDh + 16 * (f0 & 3) + 8 * g2;
  const u16* kg1 = Kb + ((size_t)(b * Ss + 32 * (f1 >> 2) + l31)) * Dd + h * HDh + 16 * (f1 & 3) + 8 * g2;
  const u16* vg0 = Vtg + ((size_t)((b * Hh + h) * HDh + 32 * (f0 >> 2) + l31)) * Ss + 16 * (f0 & 3) + 8 * g2;
  const u16* vg1 = Vtg + ((size_t)((b * Hh + h) * HDh + 32 * (f1 >> 2) + l31)) * Ss + 16 * (f1 & 3) + 8 * g2;

  auto stage = [&](int buf, int kt) {
    u16* base = &smem[buf * 8192];
    gload_lds16(kg0 + (size_t)kt * 64 * Dd, base + f0 * 512);
    gload_lds16(kg1 + (size_t)kt * 64 * Dd, base + f1 * 512);
    gload_lds16(vg0 + kt * 64, base + 4096 + f0 * 512);
    gload_lds16(vg1 + kt * 64, base + 4096 + f1 * 512);
  };

  stage(0, 0);
  __syncthreads();

  int cur = 0;
  for (int kt = 0; kt < Ss / 64; ++kt) {
    if (kt + 1 < Ss / 64) stage(cur ^ 1, kt + 1);
    const u16* sb = &smem[cur * 8192];
    const int lb = lane * 8;

    // ---- QK^T: S^T (64k x 32q), two 32-row slabs ----
    f32x16 sc0, sc1;
#pragma unroll
    for (int r = 0; r < 16; ++r) { sc0[r] = 0.f; sc1[r] = 0.f; }
    __builtin_amdgcn_s_setprio(1);
    {
      s16x8 ka, kb2;
      ka  = *(const s16x8*)&sb[(0 * 4 + 0) * 512 + lb];
      kb2 = *(const s16x8*)&sb[(1 * 4 + 0) * 512 + lb];
      sc0 = __builtin_amdgcn_mfma_f32_32x32x16_bf16(ka, qf0, sc0, 0, 0, 0);
      sc1 = __builtin_amdgcn_mfma_f32_32x32x16_bf16(kb2, qf0, sc1, 0, 0, 0);
      ka  = *(const s16x8*)&sb[(0 * 4 + 1) * 512 + lb];
      kb2 = *(const s16x8*)&sb[(1 * 4 + 1) * 512 + lb];
      sc0 = __builtin_amdgcn_mfma_f32_32x32x16_bf16(ka, qf1, sc0, 0, 0, 0);
      sc1 = __builtin_amdgcn_mfma_f32_32x32x16_bf16(kb2, qf1, sc1, 0, 0, 0);
      ka  = *(const s16x8*)&sb[(0 * 4 + 2) * 512 + lb];
      kb2 = *(const s16x8*)&sb[(1 * 4 + 2) * 512 + lb];
      sc0 = __builtin_amdgcn_mfma_f32_32x32x16_bf16(ka, qf2, sc0, 0, 0, 0);
      sc1 = __builtin_amdgcn_mfma_f32_32x32x16_bf16(kb2, qf2, sc1, 0, 0, 0);
      ka  = *(const s16x8*)&sb[(0 * 4 + 3) * 512 + lb];
      kb2 = *(const s16x8*)&sb[(1 * 4 + 3) * 512 + lb];
      sc0 = __builtin_amdgcn_mfma_f32_32x32x16_bf16(ka, qf3, sc0, 0, 0, 0);
      sc1 = __builtin_amdgcn_mfma_f32_32x32x16_bf16(kb2, qf3, sc1, 0, 0, 0);
    }
    __builtin_amdgcn_s_setprio(0);

    // ---- softmax in exp2 domain ----
    float p0[16], p1[16];
    float lp = 0.f;
#pragma unroll
    for (int r = 0; r < 16; ++r) { const float e = vexp2(sc0[r]); p0[r] = e; lp += e; }
#pragma unroll
    for (int r = 0; r < 16; ++r) { const float e = vexp2(sc1[r]); p1[r] = e; lp += e; }
    lp += __shfl_xor(lp, 32);
    l_run += lp;

    // P -> bf16 quad words (lo = first arg)
    u32 pw0[4][2], pw1[4][2];
#pragma unroll
    for (int c = 0; c < 4; ++c) {
      pw0[c][0] = cvt_pk_bf16(p0[4 * c + 0], p0[4 * c + 1]);
      pw0[c][1] = cvt_pk_bf16(p0[4 * c + 2], p0[4 * c + 3]);
      pw1[c][0] = cvt_pk_bf16(p1[4 * c + 0], p1[4 * c + 1]);
      pw1[c][1] = cvt_pk_bf16(p1[4 * c + 2], p1[4 * c + 3]);
    }

    // ---- PV: O^T += V^T @ P^T; permlane32_swap yields both pv halves ----
#pragma unroll
    for (int s = 0; s < 4; ++s) {
      const int cb = 2 * (s & 1);
      u32 A0w, B0w, A1w, B1w;
      if (s < 2) { A0w = pw0[cb][0]; B0w = pw0[cb + 1][0]; A1w = pw0[cb][1]; B1w = pw0[cb + 1][1]; }
      else       { A0w = pw1[cb][0]; B0w = pw1[cb + 1][0]; A1w = pw1[cb][1]; B1w = pw1[cb + 1][1]; }
      asm("v_permlane32_swap_b32 %0, %1" : "+v"(A0w), "+v"(B0w));
      asm("v_permlane32_swap_b32 %0, %1" : "+v"(A1w), "+v"(B1w));
      u32x4 pv;
      pv[0] = A0w; pv[1] = A1w; pv[2] = B0w; pv[3] = B1w;
      const s16x8 pf = __builtin_bit_cast(s16x8, pv);
      const s16x8 v0 = *(const s16x8*)&sb[4096 + (0 * 4 + s) * 512 + lb];
      const s16x8 v1 = *(const s16x8*)&sb[4096 + (1 * 4 + s) * 512 + lb];
      __builtin_amdgcn_s_setprio(1);
      accO0 = __builtin_amdgcn_mfma_f32_32x32x16_bf16(v0, pf, accO0, 0, 0, 0);
      accO1 = __builtin_amdgcn_mfma_f32_32x32x16_bf16(v1, pf, accO1, 0, 0, 0);
      __builtin_amdgcn_s_setprio(0);
    }
    __syncthreads();
    cur ^= 1;
  }

  // epilogue
  const float inv = 1.f / l_run;
  u16* Ol = &smem[w * 2304];
#pragma unroll
  for (int c = 0; c < 4; ++c) {
    u16x4 pk;
#pragma unroll
    for (int rr = 0; rr < 4; ++rr) pk[rr] = f2bf(accO0[4 * c + rr] * inv);
    *(u16x4*)&Ol[l31 * 72 + 0 * 32 + c * 8 + g2 * 4] = pk;
#pragma unroll
    for (int rr = 0; rr < 4; ++rr) pk[rr] = f2bf(accO1[4 * c + rr] * inv);
    *(u16x4*)&Ol[l31 * 72 + 1 * 32 + c * 8 + g2 * 4] = pk;
  }
  const size_t orow = ((size_t)(b * Ss + q0 + l31)) * Dd + h * HDh + g2 * 32;
#pragma unroll
  for (int k2 = 0; k2 < 4; ++k2) {
    const u16x8 vv = *(const u16x8*)&Ol[l31 * 72 + g2 * 32 + k2 * 8];
    *(u16x8*)(Ob + orow + k2 * 8) = vv;
  }
}

// ---------------------------------------------------------------------------
// Residual + LayerNorm (unchanged).
// ---------------------------------------------------------------------------
__global__ __launch_bounds__(256) void resid_ln_k(const float* __restrict__ x0,
                                                  const float* __restrict__ x1,
                                                  const float* __restrict__ gamma,
                                                  const float* __restrict__ beta,
                                                  float* __restrict__ out) {
  const int row = blockIdx.x;
  const int t   = threadIdx.x;
  const size_t base = (size_t)row * Dd + t * 4;
  const float4 a = *(const float4*)(x0 + base);
  const float4 c = *(const float4*)(x1 + base);
  float x[4] = {a.x + c.x, a.y + c.y, a.z + c.z, a.w + c.w};
  float s  = (x[0] + x[1]) + (x[2] + x[3]);
  float s2 = fmaf(x[0], x[0], fmaf(x[1], x[1], fmaf(x[2], x[2], x[3] * x[3])));
#pragma unroll
  for (int m = 1; m < 64; m <<= 1) {
    s  += __shfl_xor(s, m);
    s2 += __shfl_xor(s2, m);
  }
  __shared__ float red[8];
  const int wave = t >> 6;
  if ((t & 63) == 0) {
    red[wave]     = s;
    red[wave + 4] = s2;
  }
  __syncthreads();
  s  = (red[0] + red[1]) + (red[2] + red[3]);
  s2 = (red[4] + red[5]) + (red[6] + red[7]);
  const float mu  = s * (1.f / Dd);
  const float var = s2 * (1.f / Dd) - mu * mu;
  const float rs  = rsqrtf(var + kEps);
  const float4 g  = *(const float4*)(gamma + t * 4);
  const float4 be = *(const float4*)(beta + t * 4);
  float4 o;
  o.x = (x[0] - mu) * rs * g.x + be.x;
  o.y = (x[1] - mu) * rs * g.y + be.y;
  o.z = (x[2] - mu) * rs * g.z + be.z;
  o.w = (x[3] - mu) * rs * g.w + be.w;
  *(float4*)(out + base) = o;
}

// ---------------------------------------------------------------------------
// ws layout (32 MB):
//   [0,8M)   Qb bf16 (pre-scaled by kScale*log2e) -- flash writes O in place
//   [8,16M)  Kb bf16           -- dead after flash
//   [16,24M) Vtg bf16 [b][n=h*64+d][s] -- written transposed by V GEMM
//   [24,32M) Wqt,Wkt,Wvt,Wot bf16 (2 MB each)
//   [8,24M)  Xo f32 (o-projection output, overlays dead Kb+Vtg)
// d_out (16 MB) = pre-LN scratch, sequenced:
//   phase 1: Xv bf16 at [0,8M)           (dead after V GEMM)
//   phase 2: Xq [0,8M), Xk [8,16M)       (dead after QK GEMM)
//   phase 3: final LN output.
// ---------------------------------------------------------------------------
extern "C" void kernel_launch(void* const* d_in, const int* in_sizes, int n_in,
                              void* d_out, int out_size, void* d_ws,
                              size_t ws_size, hipStream_t stream) {
  const float* query = (const float*)d_in[0];
  const float* key_  = (const float*)d_in[1];
  const float* value = (const float*)d_in[2];
  const float* Wq = (const float*)d_in[3];
  const float* bq = (const float*)d_in[4];
  const float* Wk = (const float*)d_in[5];
  const float* bk = (const float*)d_in[6];
  const float* Wv = (const float*)d_in[7];
  const float* bv = (const float*)d_in[8];
  const float* Wo = (const float*)d_in[9];
  const float* bo = (const float*)d_in[10];
  const float* gamma = (const float*)d_in[11];
  const float* beta  = (const float*)d_in[12];
  float* out = (float*)d_out;

  char* ws = (char*)d_ws;
  u16* Qb  = (u16*)(ws + (size_t)0);
  u16* Kb  = (u16*)(ws + (size_t)8 * 1024 * 1024);
  u16* Vtg = (u16*)(ws + (size_t)16 * 1024 * 1024);
  u16* WtB = (u16*)(ws + (size_t)24 * 1024 * 1024);
  u16* Wqt = WtB;
  u16* Wkt = WtB + (size_t)1 * 1024 * 1024;
  u16* Wvt = WtB + (size_t)2 * 1024 * 1024;
  u16* Wot = WtB + (size_t)3 * 1024 * 1024;
  float* Xo = (float*)(ws + (size_t)8 * 1024 * 1024);
  u16* Xv = (u16*)d_out;
  u16* Xq = (u16*)d_out;
  u16* Xk = (u16*)d_out + (size_t)Mr * Dd;

  // 0a) value -> bf16 (d_out scratch), weights -> bf16 W^T
  conv_bf16_k<<<dim3(Mr * Dd / 2048, 1), 256, 0, stream>>>(value, value, Xv, Xv);
  trans_w_k<<<dim3(16, 16, 4), 256, 0, stream>>>(Wq, Wk, Wv, Wo, WtB);
  // 1a) V projection (bf16 A), written directly transposed into Vtg
  gemm_reg_k<1><<<dim3(8, 32, 1), 256, 0, stream>>>(
      Xv, Xv, Wvt, Wvt, bv, bv, Vtg, Vtg, 1.f, 1.f);
  // 1b) query/key -> bf16 (overwrites dead Xv)
  conv_bf16_k<<<dim3(Mr * Dd / 2048, 2), 256, 0, stream>>>(query, key_, Xq, Xk);
  // 1c) Q,K projections (Q pre-scaled by kScale*log2e)
  gemm_reg_k<0><<<dim3(8, 32, 2), 256, 0, stream>>>(
      Xq, Xk, Wqt, Wkt, bq, bk, Qb, Kb, kQScale, 1.f);
  // 2) MFMA flash attention, output in place over Qb
  flash_mfma_k<<<dim3(16, 16, 2), 256, 0, stream>>>(Qb, Kb, Vtg, Qb);
  // 3) output projection (bf16 A, f32 out)
  gemm_reg_k<2><<<dim3(8, 32, 1), 256, 0, stream>>>(
      Qb, Qb, Wot, Wot, bo, bo, Xo, Xo, 1.f, 1.f);
  // 4) residual + LayerNorm (overwrites d_out with the final result)
  resid_ln_k<<<Mr, 256, 0, stream>>>(query, Xo, gamma, beta, out);
}

// Round 8
// 166.960 us; speedup vs baseline: 1.3103x; 1.3103x over previous
//
#include <hip/hip_runtime.h>
#include <hip/hip_bf16.h>

#define DEVI __device__ __forceinline__

// Problem constants (fixed by the reference)
constexpr int Bb  = 2;
constexpr int Ss  = 2048;
constexpr int Dd  = 1024;
constexpr int Hh  = 16;
constexpr int HDh = 64;
constexpr int Mr  = Bb * Ss;      // 4096 rows in all GEMMs
constexpr float kEps = 1e-5f;
// kScale * log2(e), folded into the Q projection so flash uses raw 2^x
constexpr float kQScale = 0.18033688011112043f;

typedef unsigned short u16;
typedef unsigned int   u32;
typedef u16 u16x8 __attribute__((ext_vector_type(8)));
typedef u16 u16x4 __attribute__((ext_vector_type(4)));
typedef __attribute__((ext_vector_type(8)))  short s16x8;
typedef __attribute__((ext_vector_type(16))) float f32x16;
typedef __attribute__((ext_vector_type(4)))  u32   u32x4;

DEVI float bf2f(u16 u) {
  return __builtin_bit_cast(float, ((unsigned int)u) << 16);
}
DEVI u16 f2bf(float f) {  // round-to-nearest-even, finite values only
  unsigned int x = __builtin_bit_cast(unsigned int, f);
  return (u16)((x + 0x7FFFu + ((x >> 16) & 1u)) >> 16);
}
DEVI u32 cvt_pk_bf16(float a, float b) {  // HW packed f32x2 -> bf16x2, RNE
  u32 r;
  asm("v_cvt_pk_bf16_f32 %0, %1, %2" : "=v"(r) : "v"(a), "v"(b));
  return r;
}
DEVI float vexp2(float x) {  // 2^x on the TRANS pipe, no pre-multiply
  float r;
  asm("v_exp_f32 %0, %1" : "=v"(r) : "v"(x));
  return r;
}

// global -> LDS direct copy, 16B per lane (flash only).
DEVI void gload_lds16(const void* g, void* l) {
  __builtin_amdgcn_global_load_lds(
      (const __attribute__((address_space(1))) unsigned int*)(unsigned long long)(size_t)g,
      (__attribute__((address_space(3))) unsigned int*)(unsigned int)(size_t)l,
      16, 0, 0);
}

// ===========================================================================
// FRAGMENT-MAJOR layout (bf16): frag (tile t32, k-slab s) is 1 KB; lane
// l = l31 + 32*g2 holds elem [t32*32 + l31][s*16 + 8*g2 + j], j=0..7, at
// u16 offset (t32*64 + s)*512 + l*8.  A wave-load of one frag is a fully
// coalesced 16B/lane global_load_dwordx4 (the gload_lds16 address pattern).
// ===========================================================================

// ---------------------------------------------------------------------------
// pack_a_fm: X[4096][1024] f32 row-major -> bf16 fragment-major.
// 64x64 tile through swizzled LDS: coalesced f32 reads, coalesced u16x8 writes.
// grid (K/64, M/64, nz); z selects matrix.
// ---------------------------------------------------------------------------
__global__ __launch_bounds__(256) void pack_a_fm(
    const float* __restrict__ X0, const float* __restrict__ X1,
    u16* __restrict__ Y0, u16* __restrict__ Y1) {
  __shared__ u16 Tl[64 * 64];
  const int t  = threadIdx.x;
  const int k0 = blockIdx.x * 64, r0 = blockIdx.y * 64;
  const float* X = blockIdx.z ? X1 : X0;
  u16*         Y = blockIdx.z ? Y1 : Y0;
#pragma unroll
  for (int i = 0; i < 4; ++i) {
    const int idx = t + i * 256;
    const int r = idx >> 4, c4 = (idx & 15) << 2;
    const float4 v = *(const float4*)(X + (size_t)(r0 + r) * 1024 + k0 + c4);
    u16x4 p;
    p[0] = f2bf(v.x); p[1] = f2bf(v.y); p[2] = f2bf(v.z); p[3] = f2bf(v.w);
    *(u16x4*)&Tl[r * 64 + (c4 ^ (8 * (r & 7)))] = p;
  }
  __syncthreads();
#pragma unroll
  for (int i = 0; i < 2; ++i) {
    const int slot = t + i * 256;
    const int f = slot >> 6, l = slot & 63;      // frag 0..7, lane 0..63
    const int l31 = l & 31, g2 = l >> 5;
    const int r = (f >> 2) * 32 + l31;           // row within tile
    const int c = (f & 3) * 16 + g2 * 8;         // col within tile, 8-aligned
    const u16x8 v = *(const u16x8*)&Tl[r * 64 + (c ^ (8 * (r & 7)))];
    const size_t t32 = (size_t)(r0 >> 5) + (f >> 2);
    const int s = (k0 >> 4) + (f & 3);
    *(u16x8*)(Y + (t32 * 64 + s) * 512 + l * 8) = v;
  }
}

// ---------------------------------------------------------------------------
// pack_w_fm: W[k][n] f32 -> bf16 fragment-major B-layout (frag (n-tile, s):
// lane l holds W[s*16+8*g2+j][n32*32+l31]). grid (16,16,4).
// ---------------------------------------------------------------------------
__global__ __launch_bounds__(256) void pack_w_fm(
    const float* __restrict__ W0, const float* __restrict__ W1,
    const float* __restrict__ W2, const float* __restrict__ W3,
    u16* __restrict__ WfmBase) {
  __shared__ u16 Tl[64 * 64];
  const int t  = threadIdx.x;
  const int k0 = blockIdx.x * 64, n0 = blockIdx.y * 64;
  const int z  = blockIdx.z;
  const float* W = z == 0 ? W0 : z == 1 ? W1 : z == 2 ? W2 : W3;
  u16* out = WfmBase + (size_t)z * 1024 * 1024;
#pragma unroll
  for (int i = 0; i < 4; ++i) {
    const int idx = t + i * 256;
    const int r = idx >> 4, c4 = (idx & 15) << 2;   // r = k-idx, c = n-idx
    const float4 v = *(const float4*)(W + (size_t)(k0 + r) * 1024 + n0 + c4);
    u16x4 p;
    p[0] = f2bf(v.x); p[1] = f2bf(v.y); p[2] = f2bf(v.z); p[3] = f2bf(v.w);
    *(u16x4*)&Tl[r * 64 + (c4 ^ (8 * (r & 7)))] = p;
  }
  __syncthreads();
#pragma unroll
  for (int i = 0; i < 2; ++i) {
    const int slot = t + i * 256;
    const int f = slot >> 6, l = slot & 63;
    const int l31 = l & 31, g2 = l >> 5;
    const int rbase = (f & 3) * 16 + g2 * 8;         // k within tile
    const int c = (f >> 2) * 32 + l31;               // n within tile
    u16x8 o;
#pragma unroll
    for (int j = 0; j < 8; ++j) {
      const int r = rbase + j;
      o[j] = Tl[r * 64 + (((c & ~3) ^ (8 * (r & 7))) | (c & 3))];
    }
    const size_t n32 = (size_t)(n0 >> 5) + (f >> 2);
    const int s = (k0 >> 4) + (f & 3);
    *(u16x8*)(out + (n32 * 64 + s) * 512 + l * 8) = o;
  }
}

// ---------------------------------------------------------------------------
// Register-staged MFMA GEMM on FRAGMENT-MAJOR inputs. No LDS, no barriers:
// every fragment load is one coalesced 16B/lane global_load_dwordx4; X/Y
// register ping-pong; compiler emits counted vmcnt waits. 4 waves/block,
// each owns a 64x64 output quadrant. XCD-aware bijective swizzle.
// MODE 0: bf16 row-major out (esc-scaled)
// MODE 1: bf16 written transposed into Vtg[b][n][s]
// MODE 2: f32 row-major out
// ---------------------------------------------------------------------------
template <int MODE>
__global__ __launch_bounds__(256) void gemm_reg_k(
    const u16* __restrict__ A0, const u16* __restrict__ A1,
    const u16* __restrict__ Wt0, const u16* __restrict__ Wt1,
    const float* b0, const float* b1, void* C0, void* C1,
    float e0, float e1) {
  constexpr int K = 1024, N = 1024;
  const int z = blockIdx.z;
  const u16*   A    = z ? A1 : A0;
  const u16*   Wt   = z ? Wt1 : Wt0;
  const float* bias = z ? b1 : b0;
  void*        Cv   = z ? C1 : C0;
  const float  esc  = z ? e1 : e0;

  const int t = threadIdx.x;
  const int lane = t & 63, w = t >> 6;
  const int l31 = lane & 31, g2 = lane >> 5;
  // XCD swizzle (256 blocks/z-slice, 8 XCDs, chunk 32)
  const int id  = blockIdx.y * 8 + blockIdx.x;
  const int sid = (id & 7) * 32 + (id >> 3);
  const int m0 = (sid >> 3) * 128, n0 = (sid & 7) * 128;
  const int wr = w >> 1, wc = w & 1;

  // fragment-major base pointers (u16): tile stride = 64*512 u16
  const u16* a0p = A  + ((size_t)(m0 >> 5) + 2 * wr) * 32768 + lane * 8;
  const u16* a1p = a0p + 32768;
  const u16* w0p = Wt + ((size_t)(n0 >> 5) + 2 * wc) * 32768 + lane * 8;
  const u16* w1p = w0p + 32768;

  f32x16 acc00, acc01, acc10, acc11;
#pragma unroll
  for (int r = 0; r < 16; ++r) { acc00[r] = 0.f; acc01[r] = 0.f; acc10[r] = 0.f; acc11[r] = 0.f; }

  s16x8 X[8], Y[8];
  auto loadset = [&](s16x8* R, int k0) {
    const int o = (k0 >> 4) * 512;   // slab offset in u16
    R[0] = *(const s16x8*)(a0p + o);  R[1] = *(const s16x8*)(a0p + o + 512);
    R[2] = *(const s16x8*)(a1p + o);  R[3] = *(const s16x8*)(a1p + o + 512);
    R[4] = *(const s16x8*)(w0p + o);  R[5] = *(const s16x8*)(w0p + o + 512);
    R[6] = *(const s16x8*)(w1p + o);  R[7] = *(const s16x8*)(w1p + o + 512);
  };
  auto compute = [&](const s16x8* R) {
#pragma unroll
    for (int s = 0; s < 2; ++s) {
      if constexpr (MODE == 1) {
        // C col = n (A-op = X): transposed store orientation
        acc00 = __builtin_amdgcn_mfma_f32_32x32x16_bf16(R[0 + s], R[4 + s], acc00, 0, 0, 0);
        acc01 = __builtin_amdgcn_mfma_f32_32x32x16_bf16(R[0 + s], R[6 + s], acc01, 0, 0, 0);
        acc10 = __builtin_amdgcn_mfma_f32_32x32x16_bf16(R[2 + s], R[4 + s], acc10, 0, 0, 0);
        acc11 = __builtin_amdgcn_mfma_f32_32x32x16_bf16(R[2 + s], R[6 + s], acc11, 0, 0, 0);
      } else {
        // C col = m (A-op = W): row-major store orientation
        acc00 = __builtin_amdgcn_mfma_f32_32x32x16_bf16(R[4 + s], R[0 + s], acc00, 0, 0, 0);
        acc01 = __builtin_amdgcn_mfma_f32_32x32x16_bf16(R[4 + s], R[2 + s], acc01, 0, 0, 0);
        acc10 = __builtin_amdgcn_mfma_f32_32x32x16_bf16(R[6 + s], R[0 + s], acc10, 0, 0, 0);
        acc11 = __builtin_amdgcn_mfma_f32_32x32x16_bf16(R[6 + s], R[2 + s], acc11, 0, 0, 0);
      }
    }
  };

  loadset(X, 0);
  loadset(Y, 32);
  for (int k0 = 0; k0 < K; k0 += 64) {
    compute(X);
    if (k0 + 64 < K) loadset(X, k0 + 64);
    compute(Y);
    if (k0 + 96 < K) loadset(Y, k0 + 96);
  }

  if constexpr (MODE == 1) {
    auto storeV = [&](const f32x16& a, int i, int j) {
      const int n = n0 + (2 * wc + j) * 32 + l31;
      const float bn = bias[n];
      u16* vout = (u16*)Cv + ((size_t)(m0 >> 11)) * (1024 * 2048) + (size_t)n * 2048 +
                  (m0 & 2047) + (2 * wr + i) * 32;
#pragma unroll
      for (int c = 0; c < 4; ++c) {
        u16x4 o;
#pragma unroll
        for (int rr = 0; rr < 4; ++rr) o[rr] = f2bf(a[4 * c + rr] + bn);
        *(u16x4*)(vout + 8 * c + 4 * g2) = o;
      }
    };
    storeV(acc00, 0, 0); storeV(acc01, 0, 1); storeV(acc10, 1, 0); storeV(acc11, 1, 1);
  } else {
    auto storeNM = [&](const f32x16& a, int i, int j) {
      const int m = m0 + (2 * wr + j) * 32 + l31;
#pragma unroll
      for (int c = 0; c < 4; ++c) {
        const int nb = n0 + (2 * wc + i) * 32 + 8 * c + 4 * g2;
        const float4 b4 = *(const float4*)&bias[nb];
        if constexpr (MODE == 2) {
          float4 v;
          v.x = a[4 * c + 0] + b4.x; v.y = a[4 * c + 1] + b4.y;
          v.z = a[4 * c + 2] + b4.z; v.w = a[4 * c + 3] + b4.w;
          *(float4*)((float*)Cv + (size_t)m * N + nb) = v;
        } else {
          u16x4 o;
          o[0] = f2bf((a[4 * c + 0] + b4.x) * esc); o[1] = f2bf((a[4 * c + 1] + b4.y) * esc);
          o[2] = f2bf((a[4 * c + 2] + b4.z) * esc); o[3] = f2bf((a[4 * c + 3] + b4.w) * esc);
          *(u16x4*)((u16*)Cv + (size_t)m * N + nb) = o;
        }
      }
    };
    storeNM(acc00, 0, 0); storeNM(acc01, 0, 1); storeNM(acc10, 1, 0); storeNM(acc11, 1, 1);
  }
}

// ---------------------------------------------------------------------------
// MFMA flash attention (loop identical to verified rounds 4-7): LDS double-
// buffered K/V staging, exp2-domain softmax, permlane32_swap, setprio, XCD
// swizzle. EPILOGUE CHANGE: O written FRAGMENT-MAJOR (for the reg-staged
// o-projection) into Ofm — reads the same per-wave LDS transpose buffer at
// d = s*16 + 8*g2 slices instead of g2*32 + k2*8. No in-place aliasing.
// ---------------------------------------------------------------------------
__global__ __launch_bounds__(256) void flash_mfma_k(
    const u16* __restrict__ Qb, const u16* __restrict__ Kb,
    const u16* __restrict__ Vtg, u16* __restrict__ Ofm) {
  __shared__ u16 smem[16384];
  const int t    = threadIdx.x;
  const int lane = t & 63;
  const int w    = t >> 6;
  const int l31  = lane & 31, g2 = lane >> 5;
  // swizzle: 512 blocks, 8 XCDs, chunk 64
  const int hid = (blockIdx.z * 16 + blockIdx.y) * 16 + blockIdx.x;
  const int sid = (hid & 7) * 64 + (hid >> 3);
  const int h = (sid >> 4) & 15, b = sid >> 8;
  const int q0 = (sid & 15) * 128 + w * 32;

  s16x8 qf0, qf1, qf2, qf3;
  {
    const u16* qp = Qb + ((size_t)(b * Ss + q0 + l31)) * Dd + h * HDh + 8 * g2;
    qf0 = *(const s16x8*)(qp);
    qf1 = *(const s16x8*)(qp + 16);
    qf2 = *(const s16x8*)(qp + 32);
    qf3 = *(const s16x8*)(qp + 48);
  }

  f32x16 accO0, accO1;
#pragma unroll
  for (int r = 0; r < 16; ++r) { accO0[r] = 0.f; accO1[r] = 0.f; }
  float l_run = 0.f;

  const int f0 = 2 * w, f1 = 2 * w + 1;
  const u16* kg0 = Kb + ((size_t)(b * Ss + 32 * (f0 >> 2) + l31)) * Dd + h * HDh + 16 * (f0 & 3) + 8 * g2;
  const u16* kg1 = Kb + ((size_t)(b * Ss + 32 * (f1 >> 2) + l31)) * Dd + h * HDh + 16 * (f1 & 3) + 8 * g2;
  const u16* vg0 = Vtg + ((size_t)((b * Hh + h) * HDh + 32 * (f0 >> 2) + l31)) * Ss + 16 * (f0 & 3) + 8 * g2;
  const u16* vg1 = Vtg + ((size_t)((b * Hh + h) * HDh + 32 * (f1 >> 2) + l31)) * Ss + 16 * (f1 & 3) + 8 * g2;

  auto stage = [&](int buf, int kt) {
    u16* base = &smem[buf * 8192];
    gload_lds16(kg0 + (size_t)kt * 64 * Dd, base + f0 * 512);
    gload_lds16(kg1 + (size_t)kt * 64 * Dd, base + f1 * 512);
    gload_lds16(vg0 + kt * 64, base + 4096 + f0 * 512);
    gload_lds16(vg1 + kt * 64, base + 4096 + f1 * 512);
  };

  stage(0, 0);
  __syncthreads();

  int cur = 0;
  for (int kt = 0; kt < Ss / 64; ++kt) {
    if (kt + 1 < Ss / 64) stage(cur ^ 1, kt + 1);
    const u16* sb = &smem[cur * 8192];
    const int lb = lane * 8;

    // ---- QK^T: S^T (64k x 32q), two 32-row slabs ----
    f32x16 sc0, sc1;
#pragma unroll
    for (int r = 0; r < 16; ++r) { sc0[r] = 0.f; sc1[r] = 0.f; }
    __builtin_amdgcn_s_setprio(1);
    {
      s16x8 ka, kb2;
      ka  = *(const s16x8*)&sb[(0 * 4 + 0) * 512 + lb];
      kb2 = *(const s16x8*)&sb[(1 * 4 + 0) * 512 + lb];
      sc0 = __builtin_amdgcn_mfma_f32_32x32x16_bf16(ka, qf0, sc0, 0, 0, 0);
      sc1 = __builtin_amdgcn_mfma_f32_32x32x16_bf16(kb2, qf0, sc1, 0, 0, 0);
      ka  = *(const s16x8*)&sb[(0 * 4 + 1) * 512 + lb];
      kb2 = *(const s16x8*)&sb[(1 * 4 + 1) * 512 + lb];
      sc0 = __builtin_amdgcn_mfma_f32_32x32x16_bf16(ka, qf1, sc0, 0, 0, 0);
      sc1 = __builtin_amdgcn_mfma_f32_32x32x16_bf16(kb2, qf1, sc1, 0, 0, 0);
      ka  = *(const s16x8*)&sb[(0 * 4 + 2) * 512 + lb];
      kb2 = *(const s16x8*)&sb[(1 * 4 + 2) * 512 + lb];
      sc0 = __builtin_amdgcn_mfma_f32_32x32x16_bf16(ka, qf2, sc0, 0, 0, 0);
      sc1 = __builtin_amdgcn_mfma_f32_32x32x16_bf16(kb2, qf2, sc1, 0, 0, 0);
      ka  = *(const s16x8*)&sb[(0 * 4 + 3) * 512 + lb];
      kb2 = *(const s16x8*)&sb[(1 * 4 + 3) * 512 + lb];
      sc0 = __builtin_amdgcn_mfma_f32_32x32x16_bf16(ka, qf3, sc0, 0, 0, 0);
      sc1 = __builtin_amdgcn_mfma_f32_32x32x16_bf16(kb2, qf3, sc1, 0, 0, 0);
    }
    __builtin_amdgcn_s_setprio(0);

    // ---- softmax in exp2 domain ----
    float p0[16], p1[16];
    float lp = 0.f;
#pragma unroll
    for (int r = 0; r < 16; ++r) { const float e = vexp2(sc0[r]); p0[r] = e; lp += e; }
#pragma unroll
    for (int r = 0; r < 16; ++r) { const float e = vexp2(sc1[r]); p1[r] = e; lp += e; }
    lp += __shfl_xor(lp, 32);
    l_run += lp;

    // P -> bf16 quad words (lo = first arg)
    u32 pw0[4][2], pw1[4][2];
#pragma unroll
    for (int c = 0; c < 4; ++c) {
      pw0[c][0] = cvt_pk_bf16(p0[4 * c + 0], p0[4 * c + 1]);
      pw0[c][1] = cvt_pk_bf16(p0[4 * c + 2], p0[4 * c + 3]);
      pw1[c][0] = cvt_pk_bf16(p1[4 * c + 0], p1[4 * c + 1]);
      pw1[c][1] = cvt_pk_bf16(p1[4 * c + 2], p1[4 * c + 3]);
    }

    // ---- PV: O^T += V^T @ P^T; permlane32_swap yields both pv halves ----
#pragma unroll
    for (int s = 0; s < 4; ++s) {
      const int cb = 2 * (s & 1);
      u32 A0w, B0w, A1w, B1w;
      if (s < 2) { A0w = pw0[cb][0]; B0w = pw0[cb + 1][0]; A1w = pw0[cb][1]; B1w = pw0[cb + 1][1]; }
      else       { A0w = pw1[cb][0]; B0w = pw1[cb + 1][0]; A1w = pw1[cb][1]; B1w = pw1[cb + 1][1]; }
      asm("v_permlane32_swap_b32 %0, %1" : "+v"(A0w), "+v"(B0w));
      asm("v_permlane32_swap_b32 %0, %1" : "+v"(A1w), "+v"(B1w));
      u32x4 pv;
      pv[0] = A0w; pv[1] = A1w; pv[2] = B0w; pv[3] = B1w;
      const s16x8 pf = __builtin_bit_cast(s16x8, pv);
      const s16x8 v0 = *(const s16x8*)&sb[4096 + (0 * 4 + s) * 512 + lb];
      const s16x8 v1 = *(const s16x8*)&sb[4096 + (1 * 4 + s) * 512 + lb];
      __builtin_amdgcn_s_setprio(1);
      accO0 = __builtin_amdgcn_mfma_f32_32x32x16_bf16(v0, pf, accO0, 0, 0, 0);
      accO1 = __builtin_amdgcn_mfma_f32_32x32x16_bf16(v1, pf, accO1, 0, 0, 0);
      __builtin_amdgcn_s_setprio(0);
    }
    __syncthreads();
    cur ^= 1;
  }

  // epilogue: per-wave LDS transpose (verified layout: Ol[l31*72 + d] =
  // O[row l31][d]), then FRAGMENT-MAJOR global write for the o-projection.
  const float inv = 1.f / l_run;
  u16* Ol = &smem[w * 2304];
#pragma unroll
  for (int c = 0; c < 4; ++c) {
    u16x4 pk;
#pragma unroll
    for (int rr = 0; rr < 4; ++rr) pk[rr] = f2bf(accO0[4 * c + rr] * inv);
    *(u16x4*)&Ol[l31 * 72 + 0 * 32 + c * 8 + g2 * 4] = pk;
#pragma unroll
    for (int rr = 0; rr < 4; ++rr) pk[rr] = f2bf(accO1[4 * c + rr] * inv);
    *(u16x4*)&Ol[l31 * 72 + 1 * 32 + c * 8 + g2 * 4] = pk;
  }
  const size_t m32 = (size_t)((b * Ss + q0) >> 5);
#pragma unroll
  for (int s = 0; s < 4; ++s) {
    const u16x8 vv = *(const u16x8*)&Ol[l31 * 72 + s * 16 + g2 * 8];
    *(u16x8*)(Ofm + (m32 * 64 + h * 4 + s) * 512 + lane * 8) = vv;
  }
}

// ---------------------------------------------------------------------------
// Residual + LayerNorm (unchanged).
// ---------------------------------------------------------------------------
__global__ __launch_bounds__(256) void resid_ln_k(const float* __restrict__ x0,
                                                  const float* __restrict__ x1,
                                                  const float* __restrict__ gamma,
                                                  const float* __restrict__ beta,
                                                  float* __restrict__ out) {
  const int row = blockIdx.x;
  const int t   = threadIdx.x;
  const size_t base = (size_t)row * Dd + t * 4;
  const float4 a = *(const float4*)(x0 + base);
  const float4 c = *(const float4*)(x1 + base);
  float x[4] = {a.x + c.x, a.y + c.y, a.z + c.z, a.w + c.w};
  float s  = (x[0] + x[1]) + (x[2] + x[3]);
  float s2 = fmaf(x[0], x[0], fmaf(x[1], x[1], fmaf(x[2], x[2], x[3] * x[3])));
#pragma unroll
  for (int m = 1; m < 64; m <<= 1) {
    s  += __shfl_xor(s, m);
    s2 += __shfl_xor(s2, m);
  }
  __shared__ float red[8];
  const int wave = t >> 6;
  if ((t & 63) == 0) {
    red[wave]     = s;
    red[wave + 4] = s2;
  }
  __syncthreads();
  s  = (red[0] + red[1]) + (red[2] + red[3]);
  s2 = (red[4] + red[5]) + (red[6] + red[7]);
  const float mu  = s * (1.f / Dd);
  const float var = s2 * (1.f / Dd) - mu * mu;
  const float rs  = rsqrtf(var + kEps);
  const float4 g  = *(const float4*)(gamma + t * 4);
  const float4 be = *(const float4*)(beta + t * 4);
  float4 o;
  o.x = (x[0] - mu) * rs * g.x + be.x;
  o.y = (x[1] - mu) * rs * g.y + be.y;
  o.z = (x[2] - mu) * rs * g.z + be.z;
  o.w = (x[3] - mu) * rs * g.w + be.w;
  *(float4*)(out + base) = o;
}

// ---------------------------------------------------------------------------
// ws layout (32 MB):
//   [0,8M)   Qb bf16 row-major (pre-scaled by kScale*log2e)
//   [8,16M)  Kb bf16 row-major          -- dead after flash
//   [16,24M) Vtg bf16 [b][n=h*64+d][s]  -- dead after flash
//   [24,32M) Wq/Wk/Wv/Wo fragment-major bf16 (2 MB each)
//   [8,24M)  Xo f32 (o-projection output, overlays dead Kb+Vtg)
// d_out (16 MB) = scratch, sequenced:
//   phase 1: Xv_fm [0,8M)                (dead after V GEMM)
//   phase 2: Xq_fm [0,8M), Xk_fm [8,16M) (dead after QK GEMM)
//   phase 3: O_fm [0,8M)                 (dead after o-projection)
//   phase 4: final LN output.
// ---------------------------------------------------------------------------
extern "C" void kernel_launch(void* const* d_in, const int* in_sizes, int n_in,
                              void* d_out, int out_size, void* d_ws,
                              size_t ws_size, hipStream_t stream) {
  const float* query = (const float*)d_in[0];
  const float* key_  = (const float*)d_in[1];
  const float* value = (const float*)d_in[2];
  const float* Wq = (const float*)d_in[3];
  const float* bq = (const float*)d_in[4];
  const float* Wk = (const float*)d_in[5];
  const float* bk = (const float*)d_in[6];
  const float* Wv = (const float*)d_in[7];
  const float* bv = (const float*)d_in[8];
  const float* Wo = (const float*)d_in[9];
  const float* bo = (const float*)d_in[10];
  const float* gamma = (const float*)d_in[11];
  const float* beta  = (const float*)d_in[12];
  float* out = (float*)d_out;

  char* ws = (char*)d_ws;
  u16* Qb  = (u16*)(ws + (size_t)0);
  u16* Kb  = (u16*)(ws + (size_t)8 * 1024 * 1024);
  u16* Vtg = (u16*)(ws + (size_t)16 * 1024 * 1024);
  u16* WfB = (u16*)(ws + (size_t)24 * 1024 * 1024);
  u16* Wqf = WfB;
  u16* Wkf = WfB + (size_t)1 * 1024 * 1024;
  u16* Wvf = WfB + (size_t)2 * 1024 * 1024;
  u16* Wof = WfB + (size_t)3 * 1024 * 1024;
  float* Xo = (float*)(ws + (size_t)8 * 1024 * 1024);
  u16* Xv  = (u16*)d_out;
  u16* Xq  = (u16*)d_out;
  u16* Xk  = (u16*)d_out + (size_t)Mr * Dd;
  u16* Ofm = (u16*)d_out;

  // 0) value -> fragment-major bf16; weights -> fragment-major bf16
  pack_a_fm<<<dim3(16, 64, 1), 256, 0, stream>>>(value, value, Xv, Xv);
  pack_w_fm<<<dim3(16, 16, 4), 256, 0, stream>>>(Wq, Wk, Wv, Wo, WfB);
  // 1) V projection, written directly transposed into Vtg
  gemm_reg_k<1><<<dim3(8, 32, 1), 256, 0, stream>>>(
      Xv, Xv, Wvf, Wvf, bv, bv, Vtg, Vtg, 1.f, 1.f);
  // 2) query/key -> fragment-major bf16 (overwrites dead Xv)
  pack_a_fm<<<dim3(16, 64, 2), 256, 0, stream>>>(query, key_, Xq, Xk);
  // 3) Q,K projections (Q pre-scaled by kScale*log2e)
  gemm_reg_k<0><<<dim3(8, 32, 2), 256, 0, stream>>>(
      Xq, Xk, Wqf, Wkf, bq, bk, Qb, Kb, kQScale, 1.f);
  // 4) MFMA flash attention -> O fragment-major (d_out scratch)
  flash_mfma_k<<<dim3(16, 16, 2), 256, 0, stream>>>(Qb, Kb, Vtg, Ofm);
  // 5) output projection (fragment-major A, f32 out)
  gemm_reg_k<2><<<dim3(8, 32, 1), 256, 0, stream>>>(
      Ofm, Ofm, Wof, Wof, bo, bo, Xo, Xo, 1.f, 1.f);
  // 6) residual + LayerNorm (overwrites d_out with the final result)
  resid_ln_k<<<Mr, 256, 0, stream>>>(query, Xo, gamma, beta, out);
}

// Round 9
// 140.739 us; speedup vs baseline: 1.5544x; 1.1863x over previous
//
#include <hip/hip_runtime.h>
#include <hip/hip_bf16.h>

#define DEVI __device__ __forceinline__

// Problem constants (fixed by the reference)
constexpr int Bb  = 2;
constexpr int Ss  = 2048;
constexpr int Dd  = 1024;
constexpr int Hh  = 16;
constexpr int HDh = 64;
constexpr int Mr  = Bb * Ss;      // 4096 rows in all GEMMs
constexpr float kEps = 1e-5f;
// kScale * log2(e), folded into the Q projection so flash uses raw 2^x
constexpr float kQScale = 0.18033688011112043f;

typedef unsigned short u16;
typedef unsigned int   u32;
typedef u16 u16x8 __attribute__((ext_vector_type(8)));
typedef u16 u16x4 __attribute__((ext_vector_type(4)));
typedef __attribute__((ext_vector_type(8)))  short s16x8;
typedef __attribute__((ext_vector_type(16))) float f32x16;
typedef __attribute__((ext_vector_type(4)))  u32   u32x4;

DEVI float bf2f(u16 u) {
  return __builtin_bit_cast(float, ((unsigned int)u) << 16);
}
DEVI u16 f2bf(float f) {  // round-to-nearest-even, finite values only
  unsigned int x = __builtin_bit_cast(unsigned int, f);
  return (u16)((x + 0x7FFFu + ((x >> 16) & 1u)) >> 16);
}
DEVI u32 cvt_pk_bf16(float a, float b) {  // HW packed f32x2 -> bf16x2, RNE
  u32 r;
  asm("v_cvt_pk_bf16_f32 %0, %1, %2" : "=v"(r) : "v"(a), "v"(b));
  return r;
}
DEVI float vexp2(float x) {  // 2^x on the TRANS pipe, no pre-multiply
  float r;
  asm("v_exp_f32 %0, %1" : "=v"(r) : "v"(x));
  return r;
}

// global -> LDS direct copy, 16B per lane (flash only).
DEVI void gload_lds16(const void* g, void* l) {
  __builtin_amdgcn_global_load_lds(
      (const __attribute__((address_space(1))) unsigned int*)(unsigned long long)(size_t)g,
      (__attribute__((address_space(3))) unsigned int*)(unsigned int)(size_t)l,
      16, 0, 0);
}

// ===========================================================================
// FRAGMENT-MAJOR layout (bf16): frag (tile t32, k-slab s) is 1 KB; lane
// l = l31 + 32*g2 holds elem [t32*32 + l31][s*16 + 8*g2 + j], j=0..7, at
// u16 offset (t32*64 + s)*512 + l*8.  A wave-load of one frag is a fully
// coalesced 16B/lane global_load_dwordx4.
// ===========================================================================

// ---------------------------------------------------------------------------
// pack_a_fm: X[4096][1024] f32 row-major -> bf16 fragment-major.
// ---------------------------------------------------------------------------
__global__ __launch_bounds__(256) void pack_a_fm(
    const float* __restrict__ X0, const float* __restrict__ X1,
    u16* __restrict__ Y0, u16* __restrict__ Y1) {
  __shared__ u16 Tl[64 * 64];
  const int t  = threadIdx.x;
  const int k0 = blockIdx.x * 64, r0 = blockIdx.y * 64;
  const float* X = blockIdx.z ? X1 : X0;
  u16*         Y = blockIdx.z ? Y1 : Y0;
#pragma unroll
  for (int i = 0; i < 4; ++i) {
    const int idx = t + i * 256;
    const int r = idx >> 4, c4 = (idx & 15) << 2;
    const float4 v = *(const float4*)(X + (size_t)(r0 + r) * 1024 + k0 + c4);
    u16x4 p;
    p[0] = f2bf(v.x); p[1] = f2bf(v.y); p[2] = f2bf(v.z); p[3] = f2bf(v.w);
    *(u16x4*)&Tl[r * 64 + (c4 ^ (8 * (r & 7)))] = p;
  }
  __syncthreads();
#pragma unroll
  for (int i = 0; i < 2; ++i) {
    const int slot = t + i * 256;
    const int f = slot >> 6, l = slot & 63;      // frag 0..7, lane 0..63
    const int l31 = l & 31, g2 = l >> 5;
    const int r = (f >> 2) * 32 + l31;           // row within tile
    const int c = (f & 3) * 16 + g2 * 8;         // col within tile, 8-aligned
    const u16x8 v = *(const u16x8*)&Tl[r * 64 + (c ^ (8 * (r & 7)))];
    const size_t t32 = (size_t)(r0 >> 5) + (f >> 2);
    const int s = (k0 >> 4) + (f & 3);
    *(u16x8*)(Y + (t32 * 64 + s) * 512 + l * 8) = v;
  }
}

// ---------------------------------------------------------------------------
// pack_w_fm: W[k][n] f32 -> bf16 fragment-major B-layout.
// ---------------------------------------------------------------------------
__global__ __launch_bounds__(256) void pack_w_fm(
    const float* __restrict__ W0, const float* __restrict__ W1,
    const float* __restrict__ W2, const float* __restrict__ W3,
    u16* __restrict__ WfmBase) {
  __shared__ u16 Tl[64 * 64];
  const int t  = threadIdx.x;
  const int k0 = blockIdx.x * 64, n0 = blockIdx.y * 64;
  const int z  = blockIdx.z;
  const float* W = z == 0 ? W0 : z == 1 ? W1 : z == 2 ? W2 : W3;
  u16* out = WfmBase + (size_t)z * 1024 * 1024;
#pragma unroll
  for (int i = 0; i < 4; ++i) {
    const int idx = t + i * 256;
    const int r = idx >> 4, c4 = (idx & 15) << 2;   // r = k-idx, c = n-idx
    const float4 v = *(const float4*)(W + (size_t)(k0 + r) * 1024 + n0 + c4);
    u16x4 p;
    p[0] = f2bf(v.x); p[1] = f2bf(v.y); p[2] = f2bf(v.z); p[3] = f2bf(v.w);
    *(u16x4*)&Tl[r * 64 + (c4 ^ (8 * (r & 7)))] = p;
  }
  __syncthreads();
#pragma unroll
  for (int i = 0; i < 2; ++i) {
    const int slot = t + i * 256;
    const int f = slot >> 6, l = slot & 63;
    const int l31 = l & 31, g2 = l >> 5;
    const int rbase = (f & 3) * 16 + g2 * 8;         // k within tile
    const int c = (f >> 2) * 32 + l31;               // n within tile
    u16x8 o;
#pragma unroll
    for (int j = 0; j < 8; ++j) {
      const int r = rbase + j;
      o[j] = Tl[r * 64 + (((c & ~3) ^ (8 * (r & 7))) | (c & 3))];
    }
    const size_t n32 = (size_t)(n0 >> 5) + (f >> 2);
    const int s = (k0 >> 4) + (f & 3);
    *(u16x8*)(out + (n32 * 64 + s) * 512 + l * 8) = o;
  }
}

// ---------------------------------------------------------------------------
// Register-staged MFMA GEMM on FRAGMENT-MAJOR inputs, DEPTH-3 pipeline:
// three named 32-k register sets (X, Y, Z); each loadset has two 8-MFMA
// compute blocks (~512 cy) in flight ahead of it, covering L2/HBM latency.
// No LDS, no barriers; compiler emits counted vmcnt. 4 waves/block, 64x64
// output quadrant each. XCD-aware bijective swizzle.
// MODE 0: bf16 row-major out (esc-scaled)
// MODE 1: bf16 written transposed into Vtg[b][n][s]
// MODE 2: f32 row-major out
// ---------------------------------------------------------------------------
template <int MODE>
__global__ __launch_bounds__(256, 2) void gemm_reg_k(
    const u16* __restrict__ A0, const u16* __restrict__ A1,
    const u16* __restrict__ Wt0, const u16* __restrict__ Wt1,
    const float* b0, const float* b1, void* C0, void* C1,
    float e0, float e1) {
  constexpr int K = 1024, N = 1024;
  const int z = blockIdx.z;
  const u16*   A    = z ? A1 : A0;
  const u16*   Wt   = z ? Wt1 : Wt0;
  const float* bias = z ? b1 : b0;
  void*        Cv   = z ? C1 : C0;
  const float  esc  = z ? e1 : e0;

  const int t = threadIdx.x;
  const int lane = t & 63, w = t >> 6;
  const int l31 = lane & 31, g2 = lane >> 5;
  // XCD swizzle (256 blocks/z-slice, 8 XCDs, chunk 32)
  const int id  = blockIdx.y * 8 + blockIdx.x;
  const int sid = (id & 7) * 32 + (id >> 3);
  const int m0 = (sid >> 3) * 128, n0 = (sid & 7) * 128;
  const int wr = w >> 1, wc = w & 1;

  // fragment-major base pointers (u16): tile stride = 64*512 u16
  const u16* a0p = A  + ((size_t)(m0 >> 5) + 2 * wr) * 32768 + lane * 8;
  const u16* a1p = a0p + 32768;
  const u16* w0p = Wt + ((size_t)(n0 >> 5) + 2 * wc) * 32768 + lane * 8;
  const u16* w1p = w0p + 32768;

  f32x16 acc00, acc01, acc10, acc11;
#pragma unroll
  for (int r = 0; r < 16; ++r) { acc00[r] = 0.f; acc01[r] = 0.f; acc10[r] = 0.f; acc11[r] = 0.f; }

  s16x8 X[8], Y[8], Z[8];
  auto loadset = [&](s16x8* R, int k0) {
    const int o = (k0 >> 4) * 512;   // slab offset in u16
    R[0] = *(const s16x8*)(a0p + o);  R[1] = *(const s16x8*)(a0p + o + 512);
    R[2] = *(const s16x8*)(a1p + o);  R[3] = *(const s16x8*)(a1p + o + 512);
    R[4] = *(const s16x8*)(w0p + o);  R[5] = *(const s16x8*)(w0p + o + 512);
    R[6] = *(const s16x8*)(w1p + o);  R[7] = *(const s16x8*)(w1p + o + 512);
  };
  auto compute = [&](const s16x8* R) {
#pragma unroll
    for (int s = 0; s < 2; ++s) {
      if constexpr (MODE == 1) {
        // C col = n (A-op = X): transposed store orientation
        acc00 = __builtin_amdgcn_mfma_f32_32x32x16_bf16(R[0 + s], R[4 + s], acc00, 0, 0, 0);
        acc01 = __builtin_amdgcn_mfma_f32_32x32x16_bf16(R[0 + s], R[6 + s], acc01, 0, 0, 0);
        acc10 = __builtin_amdgcn_mfma_f32_32x32x16_bf16(R[2 + s], R[4 + s], acc10, 0, 0, 0);
        acc11 = __builtin_amdgcn_mfma_f32_32x32x16_bf16(R[2 + s], R[6 + s], acc11, 0, 0, 0);
      } else {
        // C col = m (A-op = W): row-major store orientation
        acc00 = __builtin_amdgcn_mfma_f32_32x32x16_bf16(R[4 + s], R[0 + s], acc00, 0, 0, 0);
        acc01 = __builtin_amdgcn_mfma_f32_32x32x16_bf16(R[4 + s], R[2 + s], acc01, 0, 0, 0);
        acc10 = __builtin_amdgcn_mfma_f32_32x32x16_bf16(R[6 + s], R[0 + s], acc10, 0, 0, 0);
        acc11 = __builtin_amdgcn_mfma_f32_32x32x16_bf16(R[6 + s], R[2 + s], acc11, 0, 0, 0);
      }
    }
  };

  // 32 chunks of 32-k; depth-3 schedule: preload c0..c2, then steady-state
  // {compute(c); load(c+3)} -- every load has 2 compute blocks to land.
  loadset(X, 0); loadset(Y, 32); loadset(Z, 64);
  int k = 0;
  for (int it = 0; it < 9; ++it, k += 96) {
    compute(X); loadset(X, k + 96);
    compute(Y); loadset(Y, k + 128);
    compute(Z); loadset(Z, k + 160);
  }
  // chunks 27..31 (k = 864..992)
  compute(X); loadset(X, 960);
  compute(Y); loadset(Y, 992);
  compute(Z);
  compute(X);
  compute(Y);

  if constexpr (MODE == 1) {
    auto storeV = [&](const f32x16& a, int i, int j) {
      const int n = n0 + (2 * wc + j) * 32 + l31;
      const float bn = bias[n];
      u16* vout = (u16*)Cv + ((size_t)(m0 >> 11)) * (1024 * 2048) + (size_t)n * 2048 +
                  (m0 & 2047) + (2 * wr + i) * 32;
#pragma unroll
      for (int c = 0; c < 4; ++c) {
        u16x4 o;
#pragma unroll
        for (int rr = 0; rr < 4; ++rr) o[rr] = f2bf(a[4 * c + rr] + bn);
        *(u16x4*)(vout + 8 * c + 4 * g2) = o;
      }
    };
    storeV(acc00, 0, 0); storeV(acc01, 0, 1); storeV(acc10, 1, 0); storeV(acc11, 1, 1);
  } else {
    auto storeNM = [&](const f32x16& a, int i, int j) {
      const int m = m0 + (2 * wr + j) * 32 + l31;
#pragma unroll
      for (int c = 0; c < 4; ++c) {
        const int nb = n0 + (2 * wc + i) * 32 + 8 * c + 4 * g2;
        const float4 b4 = *(const float4*)&bias[nb];
        if constexpr (MODE == 2) {
          float4 v;
          v.x = a[4 * c + 0] + b4.x; v.y = a[4 * c + 1] + b4.y;
          v.z = a[4 * c + 2] + b4.z; v.w = a[4 * c + 3] + b4.w;
          *(float4*)((float*)Cv + (size_t)m * N + nb) = v;
        } else {
          u16x4 o;
          o[0] = f2bf((a[4 * c + 0] + b4.x) * esc); o[1] = f2bf((a[4 * c + 1] + b4.y) * esc);
          o[2] = f2bf((a[4 * c + 2] + b4.z) * esc); o[3] = f2bf((a[4 * c + 3] + b4.w) * esc);
          *(u16x4*)((u16*)Cv + (size_t)m * N + nb) = o;
        }
      }
    };
    storeNM(acc00, 0, 0); storeNM(acc01, 0, 1); storeNM(acc10, 1, 0); storeNM(acc11, 1, 1);
  }
}

// ---------------------------------------------------------------------------
// MFMA flash attention (loop identical to verified rounds 4-8): LDS double-
// buffered K/V staging, exp2-domain softmax, permlane32_swap, setprio, XCD
// swizzle, fragment-major O epilogue. CHANGE: QK^T first MFMA pair consumes a
// persistent zero C-vector (kills 32 per-tile zero movs).
// ---------------------------------------------------------------------------
__global__ __launch_bounds__(256) void flash_mfma_k(
    const u16* __restrict__ Qb, const u16* __restrict__ Kb,
    const u16* __restrict__ Vtg, u16* __restrict__ Ofm) {
  __shared__ u16 smem[16384];
  const int t    = threadIdx.x;
  const int lane = t & 63;
  const int w    = t >> 6;
  const int l31  = lane & 31, g2 = lane >> 5;
  // swizzle: 512 blocks, 8 XCDs, chunk 64
  const int hid = (blockIdx.z * 16 + blockIdx.y) * 16 + blockIdx.x;
  const int sid = (hid & 7) * 64 + (hid >> 3);
  const int h = (sid >> 4) & 15, b = sid >> 8;
  const int q0 = (sid & 15) * 128 + w * 32;

  s16x8 qf0, qf1, qf2, qf3;
  {
    const u16* qp = Qb + ((size_t)(b * Ss + q0 + l31)) * Dd + h * HDh + 8 * g2;
    qf0 = *(const s16x8*)(qp);
    qf1 = *(const s16x8*)(qp + 16);
    qf2 = *(const s16x8*)(qp + 32);
    qf3 = *(const s16x8*)(qp + 48);
  }

  f32x16 accO0, accO1, zacc;
#pragma unroll
  for (int r = 0; r < 16; ++r) { accO0[r] = 0.f; accO1[r] = 0.f; zacc[r] = 0.f; }
  float l_run = 0.f;

  const int f0 = 2 * w, f1 = 2 * w + 1;
  const u16* kg0 = Kb + ((size_t)(b * Ss + 32 * (f0 >> 2) + l31)) * Dd + h * HDh + 16 * (f0 & 3) + 8 * g2;
  const u16* kg1 = Kb + ((size_t)(b * Ss + 32 * (f1 >> 2) + l31)) * Dd + h * HDh + 16 * (f1 & 3) + 8 * g2;
  const u16* vg0 = Vtg + ((size_t)((b * Hh + h) * HDh + 32 * (f0 >> 2) + l31)) * Ss + 16 * (f0 & 3) + 8 * g2;
  const u16* vg1 = Vtg + ((size_t)((b * Hh + h) * HDh + 32 * (f1 >> 2) + l31)) * Ss + 16 * (f1 & 3) + 8 * g2;

  auto stage = [&](int buf, int kt) {
    u16* base = &smem[buf * 8192];
    gload_lds16(kg0 + (size_t)kt * 64 * Dd, base + f0 * 512);
    gload_lds16(kg1 + (size_t)kt * 64 * Dd, base + f1 * 512);
    gload_lds16(vg0 + kt * 64, base + 4096 + f0 * 512);
    gload_lds16(vg1 + kt * 64, base + 4096 + f1 * 512);
  };

  stage(0, 0);
  __syncthreads();

  int cur = 0;
  for (int kt = 0; kt < Ss / 64; ++kt) {
    if (kt + 1 < Ss / 64) stage(cur ^ 1, kt + 1);
    const u16* sb = &smem[cur * 8192];
    const int lb = lane * 8;

    // ---- QK^T: S^T (64k x 32q), two 32-row slabs; first pair seeds from
    // the persistent zero vector ----
    f32x16 sc0, sc1;
    __builtin_amdgcn_s_setprio(1);
    {
      s16x8 ka, kb2;
      ka  = *(const s16x8*)&sb[(0 * 4 + 0) * 512 + lb];
      kb2 = *(const s16x8*)&sb[(1 * 4 + 0) * 512 + lb];
      sc0 = __builtin_amdgcn_mfma_f32_32x32x16_bf16(ka, qf0, zacc, 0, 0, 0);
      sc1 = __builtin_amdgcn_mfma_f32_32x32x16_bf16(kb2, qf0, zacc, 0, 0, 0);
      ka  = *(const s16x8*)&sb[(0 * 4 + 1) * 512 + lb];
      kb2 = *(const s16x8*)&sb[(1 * 4 + 1) * 512 + lb];
      sc0 = __builtin_amdgcn_mfma_f32_32x32x16_bf16(ka, qf1, sc0, 0, 0, 0);
      sc1 = __builtin_amdgcn_mfma_f32_32x32x16_bf16(kb2, qf1, sc1, 0, 0, 0);
      ka  = *(const s16x8*)&sb[(0 * 4 + 2) * 512 + lb];
      kb2 = *(const s16x8*)&sb[(1 * 4 + 2) * 512 + lb];
      sc0 = __builtin_amdgcn_mfma_f32_32x32x16_bf16(ka, qf2, sc0, 0, 0, 0);
      sc1 = __builtin_amdgcn_mfma_f32_32x32x16_bf16(kb2, qf2, sc1, 0, 0, 0);
      ka  = *(const s16x8*)&sb[(0 * 4 + 3) * 512 + lb];
      kb2 = *(const s16x8*)&sb[(1 * 4 + 3) * 512 + lb];
      sc0 = __builtin_amdgcn_mfma_f32_32x32x16_bf16(ka, qf3, sc0, 0, 0, 0);
      sc1 = __builtin_amdgcn_mfma_f32_32x32x16_bf16(kb2, qf3, sc1, 0, 0, 0);
    }
    __builtin_amdgcn_s_setprio(0);

    // ---- softmax in exp2 domain ----
    float p0[16], p1[16];
    float lp = 0.f;
#pragma unroll
    for (int r = 0; r < 16; ++r) { const float e = vexp2(sc0[r]); p0[r] = e; lp += e; }
#pragma unroll
    for (int r = 0; r < 16; ++r) { const float e = vexp2(sc1[r]); p1[r] = e; lp += e; }
    lp += __shfl_xor(lp, 32);
    l_run += lp;

    // P -> bf16 quad words (lo = first arg)
    u32 pw0[4][2], pw1[4][2];
#pragma unroll
    for (int c = 0; c < 4; ++c) {
      pw0[c][0] = cvt_pk_bf16(p0[4 * c + 0], p0[4 * c + 1]);
      pw0[c][1] = cvt_pk_bf16(p0[4 * c + 2], p0[4 * c + 3]);
      pw1[c][0] = cvt_pk_bf16(p1[4 * c + 0], p1[4 * c + 1]);
      pw1[c][1] = cvt_pk_bf16(p1[4 * c + 2], p1[4 * c + 3]);
    }

    // ---- PV: O^T += V^T @ P^T; permlane32_swap yields both pv halves ----
#pragma unroll
    for (int s = 0; s < 4; ++s) {
      const int cb = 2 * (s & 1);
      u32 A0w, B0w, A1w, B1w;
      if (s < 2) { A0w = pw0[cb][0]; B0w = pw0[cb + 1][0]; A1w = pw0[cb][1]; B1w = pw0[cb + 1][1]; }
      else       { A0w = pw1[cb][0]; B0w = pw1[cb + 1][0]; A1w = pw1[cb][1]; B1w = pw1[cb + 1][1]; }
      asm("v_permlane32_swap_b32 %0, %1" : "+v"(A0w), "+v"(B0w));
      asm("v_permlane32_swap_b32 %0, %1" : "+v"(A1w), "+v"(B1w));
      u32x4 pv;
      pv[0] = A0w; pv[1] = A1w; pv[2] = B0w; pv[3] = B1w;
      const s16x8 pf = __builtin_bit_cast(s16x8, pv);
      const s16x8 v0 = *(const s16x8*)&sb[4096 + (0 * 4 + s) * 512 + lb];
      const s16x8 v1 = *(const s16x8*)&sb[4096 + (1 * 4 + s) * 512 + lb];
      __builtin_amdgcn_s_setprio(1);
      accO0 = __builtin_amdgcn_mfma_f32_32x32x16_bf16(v0, pf, accO0, 0, 0, 0);
      accO1 = __builtin_amdgcn_mfma_f32_32x32x16_bf16(v1, pf, accO1, 0, 0, 0);
      __builtin_amdgcn_s_setprio(0);
    }
    __syncthreads();
    cur ^= 1;
  }

  // epilogue: per-wave LDS transpose, then FRAGMENT-MAJOR global write.
  const float inv = 1.f / l_run;
  u16* Ol = &smem[w * 2304];
#pragma unroll
  for (int c = 0; c < 4; ++c) {
    u16x4 pk;
#pragma unroll
    for (int rr = 0; rr < 4; ++rr) pk[rr] = f2bf(accO0[4 * c + rr] * inv);
    *(u16x4*)&Ol[l31 * 72 + 0 * 32 + c * 8 + g2 * 4] = pk;
#pragma unroll
    for (int rr = 0; rr < 4; ++rr) pk[rr] = f2bf(accO1[4 * c + rr] * inv);
    *(u16x4*)&Ol[l31 * 72 + 1 * 32 + c * 8 + g2 * 4] = pk;
  }
  const size_t m32 = (size_t)((b * Ss + q0) >> 5);
#pragma unroll
  for (int s = 0; s < 4; ++s) {
    const u16x8 vv = *(const u16x8*)&Ol[l31 * 72 + s * 16 + g2 * 8];
    *(u16x8*)(Ofm + (m32 * 64 + h * 4 + s) * 512 + lane * 8) = vv;
  }
}

// ---------------------------------------------------------------------------
// Residual + LayerNorm (unchanged).
// ---------------------------------------------------------------------------
__global__ __launch_bounds__(256) void resid_ln_k(const float* __restrict__ x0,
                                                  const float* __restrict__ x1,
                                                  const float* __restrict__ gamma,
                                                  const float* __restrict__ beta,
                                                  float* __restrict__ out) {
  const int row = blockIdx.x;
  const int t   = threadIdx.x;
  const size_t base = (size_t)row * Dd + t * 4;
  const float4 a = *(const float4*)(x0 + base);
  const float4 c = *(const float4*)(x1 + base);
  float x[4] = {a.x + c.x, a.y + c.y, a.z + c.z, a.w + c.w};
  float s  = (x[0] + x[1]) + (x[2] + x[3]);
  float s2 = fmaf(x[0], x[0], fmaf(x[1], x[1], fmaf(x[2], x[2], x[3] * x[3])));
#pragma unroll
  for (int m = 1; m < 64; m <<= 1) {
    s  += __shfl_xor(s, m);
    s2 += __shfl_xor(s2, m);
  }
  __shared__ float red[8];
  const int wave = t >> 6;
  if ((t & 63) == 0) {
    red[wave]     = s;
    red[wave + 4] = s2;
  }
  __syncthreads();
  s  = (red[0] + red[1]) + (red[2] + red[3]);
  s2 = (red[4] + red[5]) + (red[6] + red[7]);
  const float mu  = s * (1.f / Dd);
  const float var = s2 * (1.f / Dd) - mu * mu;
  const float rs  = rsqrtf(var + kEps);
  const float4 g  = *(const float4*)(gamma + t * 4);
  const float4 be = *(const float4*)(beta + t * 4);
  float4 o;
  o.x = (x[0] - mu) * rs * g.x + be.x;
  o.y = (x[1] - mu) * rs * g.y + be.y;
  o.z = (x[2] - mu) * rs * g.z + be.z;
  o.w = (x[3] - mu) * rs * g.w + be.w;
  *(float4*)(out + base) = o;
}

// ---------------------------------------------------------------------------
// ws layout (32 MB):
//   [0,8M)   Qb bf16 row-major (pre-scaled by kScale*log2e)
//   [8,16M)  Kb bf16 row-major          -- dead after flash
//   [16,24M) Vtg bf16 [b][n=h*64+d][s]  -- dead after flash
//   [24,32M) Wq/Wk/Wv/Wo fragment-major bf16 (2 MB each)
//   [8,24M)  Xo f32 (o-projection output, overlays dead Kb+Vtg)
// d_out (16 MB) = scratch, sequenced:
//   phase 1: Xv_fm [0,8M)                (dead after V GEMM)
//   phase 2: Xq_fm [0,8M), Xk_fm [8,16M) (dead after QK GEMM)
//   phase 3: O_fm [0,8M)                 (dead after o-projection)
//   phase 4: final LN output.
// ---------------------------------------------------------------------------
extern "C" void kernel_launch(void* const* d_in, const int* in_sizes, int n_in,
                              void* d_out, int out_size, void* d_ws,
                              size_t ws_size, hipStream_t stream) {
  const float* query = (const float*)d_in[0];
  const float* key_  = (const float*)d_in[1];
  const float* value = (const float*)d_in[2];
  const float* Wq = (const float*)d_in[3];
  const float* bq = (const float*)d_in[4];
  const float* Wk = (const float*)d_in[5];
  const float* bk = (const float*)d_in[6];
  const float* Wv = (const float*)d_in[7];
  const float* bv = (const float*)d_in[8];
  const float* Wo = (const float*)d_in[9];
  const float* bo = (const float*)d_in[10];
  const float* gamma = (const float*)d_in[11];
  const float* beta  = (const float*)d_in[12];
  float* out = (float*)d_out;

  char* ws = (char*)d_ws;
  u16* Qb  = (u16*)(ws + (size_t)0);
  u16* Kb  = (u16*)(ws + (size_t)8 * 1024 * 1024);
  u16* Vtg = (u16*)(ws + (size_t)16 * 1024 * 1024);
  u16* WfB = (u16*)(ws + (size_t)24 * 1024 * 1024);
  u16* Wqf = WfB;
  u16* Wkf = WfB + (size_t)1 * 1024 * 1024;
  u16* Wvf = WfB + (size_t)2 * 1024 * 1024;
  u16* Wof = WfB + (size_t)3 * 1024 * 1024;
  float* Xo = (float*)(ws + (size_t)8 * 1024 * 1024);
  u16* Xv  = (u16*)d_out;
  u16* Xq  = (u16*)d_out;
  u16* Xk  = (u16*)d_out + (size_t)Mr * Dd;
  u16* Ofm = (u16*)d_out;

  // 0) value -> fragment-major bf16; weights -> fragment-major bf16
  pack_a_fm<<<dim3(16, 64, 1), 256, 0, stream>>>(value, value, Xv, Xv);
  pack_w_fm<<<dim3(16, 16, 4), 256, 0, stream>>>(Wq, Wk, Wv, Wo, WfB);
  // 1) V projection, written directly transposed into Vtg
  gemm_reg_k<1><<<dim3(8, 32, 1), 256, 0, stream>>>(
      Xv, Xv, Wvf, Wvf, bv, bv, Vtg, Vtg, 1.f, 1.f);
  // 2) query/key -> fragment-major bf16 (overwrites dead Xv)
  pack_a_fm<<<dim3(16, 64, 2), 256, 0, stream>>>(query, key_, Xq, Xk);
  // 3) Q,K projections (Q pre-scaled by kScale*log2e)
  gemm_reg_k<0><<<dim3(8, 32, 2), 256, 0, stream>>>(
      Xq, Xk, Wqf, Wkf, bq, bk, Qb, Kb, kQScale, 1.f);
  // 4) MFMA flash attention -> O fragment-major (d_out scratch)
  flash_mfma_k<<<dim3(16, 16, 2), 256, 0, stream>>>(Qb, Kb, Vtg, Ofm);
  // 5) output projection (fragment-major A, f32 out)
  gemm_reg_k<2><<<dim3(8, 32, 1), 256, 0, stream>>>(
      Ofm, Ofm, Wof, Wof, bo, bo, Xo, Xo, 1.f, 1.f);
  // 6) residual + LayerNorm (overwrites d_out with the final result)
  resid_ln_k<<<Mr, 256, 0, stream>>>(query, Xo, gamma, beta, out);
}